// Round 14
// baseline (216.879 us; speedup 1.0000x reference)
//
#include <hip/hip_runtime.h>
#include <hip/hip_bf16.h>
#include <cstdint>
#include <cstddef>

#define BT    16384   // B*T
#define DIN   4096
#define DOUT  4096
#define RR    64
#define TSEQ  2048
#define NADP  8

typedef float  f32x4  __attribute__((ext_vector_type(4)));
typedef __bf16 bf16x8 __attribute__((ext_vector_type(8)));

static __device__ __forceinline__ unsigned short bf16_bits(float f) {
    return __builtin_bit_cast(unsigned short, (__bf16)f);
}

// inter2 swizzled layout: [mblk(1024)][rb(8)][mrow(16)][j(8)]
static __device__ __forceinline__ size_t i2_idx(int mblk, int rb, int mrow, int j) {
    return ((((size_t)mblk * 8 + rb) * 16 + mrow) * 8 + j);
}

static __device__ __forceinline__ bf16x8 cvt8(float4 a, float4 b) {
    bf16x8 v;
    v[0] = (__bf16)a.x; v[1] = (__bf16)a.y; v[2] = (__bf16)a.z; v[3] = (__bf16)a.w;
    v[4] = (__bf16)b.x; v[5] = (__bf16)b.y; v[6] = (__bf16)b.z; v[7] = (__bf16)b.w;
    return v;
}

// ---------------------------------------------------------------------------
// k_prep_a: At2[a][kq][r][j] = bf16(A[a][kq*8+j][r]).  (R8+ verbatim)
// ---------------------------------------------------------------------------
__global__ __launch_bounds__(256) void k_prep_a(
    const float* __restrict__ A, __bf16* __restrict__ At2)
{
    const int gtid = blockIdx.x * 256 + threadIdx.x;
    const int r  = gtid & 63;
    const int kb = (gtid >> 6) & (DIN / 8 - 1);
    const int a  = gtid >> 15;
    const float* __restrict__ src = A + (size_t)a * DIN * RR + (size_t)kb * 8 * RR + r;
    unsigned int u[4];
    #pragma unroll
    for (int p = 0; p < 4; ++p) {
        unsigned int lo = bf16_bits(src[(2 * p + 0) * RR]);
        unsigned int hi = bf16_bits(src[(2 * p + 1) * RR]);
        u[p] = lo | (hi << 16);
    }
    *(uint4*)&At2[(size_t)gtid * 8] = make_uint4(u[0], u[1], u[2], u[3]);
}

// ---------------------------------------------------------------------------
// k_prep_b: Bp[a][rb][o][j] = bf16(B[a][rb*8+j][o]).  (R8+ verbatim)
// ---------------------------------------------------------------------------
__global__ __launch_bounds__(256) void k_prep_b(
    const float* __restrict__ Bw, __bf16* __restrict__ Bp)
{
    const int gtid = blockIdx.x * 256 + threadIdx.x;
    const int o  = gtid & (DOUT - 1);
    const int rb = (gtid >> 12) & 7;
    const int a  = gtid >> 15;
    const float* __restrict__ src = Bw + (size_t)a * RR * DOUT + (size_t)rb * 8 * DOUT + o;
    unsigned int u[4];
    #pragma unroll
    for (int p = 0; p < 4; ++p) {
        unsigned int lo = bf16_bits(src[(2 * p + 0) * DOUT]);
        unsigned int hi = bf16_bits(src[(2 * p + 1) * DOUT]);
        u[p] = lo | (hi << 16);
    }
    *(uint4*)&Bp[(size_t)gtid * 8] = make_uint4(u[0], u[1], u[2], u[3]);
}

// ---------------------------------------------------------------------------
// k_xa: inter2 <- bf16( x @ A[a] ).  grid 256 blocks x 4 waves.
// Wave w: 16 m-rows x 64 r, full K, WAVE-PRIVATE LDS x-tile (double-buffered,
// XOR-swizzled) — ZERO __syncthreads, so prefetch loads survive across tiles
// (counted vmcnt, not the barrier's vmcnt(0) drain). COMPUTE issues all 10
// loads first, then 8 MFMAs (4 independent chains).
// LDS convention (R13-proven): xs[w][buf][r][slot j] holds x-octet j^(r&7).
// ---------------------------------------------------------------------------
__global__ __launch_bounds__(256, 1) void k_xa(
    const float* __restrict__ x, const int* __restrict__ idx,
    const __bf16* __restrict__ At2, __bf16* __restrict__ inter2)
{
    __shared__ __bf16 xs[4][2][16][64];   // 16 KB, wave-private slices

    const int m0   = blockIdx.x * 64;
    const int a    = idx[m0 / TSEQ];
    const int w    = threadIdx.x >> 6, lane = threadIdx.x & 63;
    const int mr   = lane & 15, kg = lane >> 4;

    // staging: row = mr, octets kg and kg+4 (linear source, swizzled dst slot)
    const float* __restrict__ xsrc = x + (size_t)(m0 + w * 16 + mr) * DIN;
    const int sw1 = (kg     ^ (mr & 7)) * 8;       // dst slot for octet kg
    const int sw2 = ((kg+4) ^ (mr & 7)) * 8;       // dst slot for octet kg+4
    __bf16* const dE1 = &xs[w][0][mr][sw1];
    __bf16* const dE2 = &xs[w][0][mr][sw2];
    __bf16* const dO1 = &xs[w][1][mr][sw1];
    __bf16* const dO2 = &xs[w][1][mr][sw2];

    const __bf16* __restrict__ Aw = At2 + (size_t)a * RR * DIN;

    f32x4 z = {0.f, 0.f, 0.f, 0.f};
    f32x4 acc[4] = {z, z, z, z};

    // named staging regs (rule #20): E = even buffer's next tile, O = odd's
    float4 e0, e1, e2, e3, o0, o1, o2, o3;

    // prologue: load tile0 -> E, tile1 -> O; write tile0 to buf0
    e0 = *(const float4*)(xsrc + 0 * 64 + kg * 8);
    e1 = *(const float4*)(xsrc + 0 * 64 + kg * 8 + 4);
    e2 = *(const float4*)(xsrc + 0 * 64 + (kg + 4) * 8);
    e3 = *(const float4*)(xsrc + 0 * 64 + (kg + 4) * 8 + 4);
    o0 = *(const float4*)(xsrc + 1 * 64 + kg * 8);
    o1 = *(const float4*)(xsrc + 1 * 64 + kg * 8 + 4);
    o2 = *(const float4*)(xsrc + 1 * 64 + (kg + 4) * 8);
    o3 = *(const float4*)(xsrc + 1 * 64 + (kg + 4) * 8 + 4);
    *(bf16x8*)dE1 = cvt8(e0, e1);
    *(bf16x8*)dE2 = cvt8(e2, e3);

#define COMPUTE(BUF, T)                                                        \
    {                                                                          \
        bf16x8 b00 = *(const bf16x8*)&Aw[(((size_t)(T)*8 + 0*4 + kg)*64 +  0 + mr)*8]; \
        bf16x8 b01 = *(const bf16x8*)&Aw[(((size_t)(T)*8 + 0*4 + kg)*64 + 16 + mr)*8]; \
        bf16x8 b02 = *(const bf16x8*)&Aw[(((size_t)(T)*8 + 0*4 + kg)*64 + 32 + mr)*8]; \
        bf16x8 b03 = *(const bf16x8*)&Aw[(((size_t)(T)*8 + 0*4 + kg)*64 + 48 + mr)*8]; \
        bf16x8 b10 = *(const bf16x8*)&Aw[(((size_t)(T)*8 + 1*4 + kg)*64 +  0 + mr)*8]; \
        bf16x8 b11 = *(const bf16x8*)&Aw[(((size_t)(T)*8 + 1*4 + kg)*64 + 16 + mr)*8]; \
        bf16x8 b12 = *(const bf16x8*)&Aw[(((size_t)(T)*8 + 1*4 + kg)*64 + 32 + mr)*8]; \
        bf16x8 b13 = *(const bf16x8*)&Aw[(((size_t)(T)*8 + 1*4 + kg)*64 + 48 + mr)*8]; \
        bf16x8 af0 = *(const bf16x8*)&xs[w][BUF][mr][((0*4 + kg) ^ (mr & 7)) * 8];     \
        bf16x8 af1 = *(const bf16x8*)&xs[w][BUF][mr][((1*4 + kg) ^ (mr & 7)) * 8];     \
        acc[0] = __builtin_amdgcn_mfma_f32_16x16x32_bf16(af0, b00, acc[0], 0, 0, 0);   \
        acc[1] = __builtin_amdgcn_mfma_f32_16x16x32_bf16(af0, b01, acc[1], 0, 0, 0);   \
        acc[2] = __builtin_amdgcn_mfma_f32_16x16x32_bf16(af0, b02, acc[2], 0, 0, 0);   \
        acc[3] = __builtin_amdgcn_mfma_f32_16x16x32_bf16(af0, b03, acc[3], 0, 0, 0);   \
        acc[0] = __builtin_amdgcn_mfma_f32_16x16x32_bf16(af1, b10, acc[0], 0, 0, 0);   \
        acc[1] = __builtin_amdgcn_mfma_f32_16x16x32_bf16(af1, b11, acc[1], 0, 0, 0);   \
        acc[2] = __builtin_amdgcn_mfma_f32_16x16x32_bf16(af1, b12, acc[2], 0, 0, 0);   \
        acc[3] = __builtin_amdgcn_mfma_f32_16x16x32_bf16(af1, b13, acc[3], 0, 0, 0);   \
    }

    for (int t2 = 0; t2 < 32; ++t2) {
        const int t   = 2 * t2;
        const int tp2 = (t + 2 <= 63) ? (t + 2) : 63;
        const int tp3 = (t + 3 <= 63) ? (t + 3) : 63;

        // refill E with tile t+2 (loads stay in flight; no barrier to drain them)
        e0 = *(const float4*)(xsrc + tp2 * 64 + kg * 8);
        e1 = *(const float4*)(xsrc + tp2 * 64 + kg * 8 + 4);
        e2 = *(const float4*)(xsrc + tp2 * 64 + (kg + 4) * 8);
        e3 = *(const float4*)(xsrc + tp2 * 64 + (kg + 4) * 8 + 4);
        COMPUTE(0, t)
        *(bf16x8*)dO1 = cvt8(o0, o1);      // tile t+1 -> buf1 (o-regs ready)
        *(bf16x8*)dO2 = cvt8(o2, o3);

        o0 = *(const float4*)(xsrc + tp3 * 64 + kg * 8);
        o1 = *(const float4*)(xsrc + tp3 * 64 + kg * 8 + 4);
        o2 = *(const float4*)(xsrc + tp3 * 64 + (kg + 4) * 8);
        o3 = *(const float4*)(xsrc + tp3 * 64 + (kg + 4) * 8 + 4);
        COMPUTE(1, t + 1)
        *(bf16x8*)dE1 = cvt8(e0, e1);      // tile t+2 -> buf0
        *(bf16x8*)dE2 = cvt8(e2, e3);
    }
#undef COMPUTE

    // D layout (R11 convention): m = m0+w*16+kg*4+q, r = n*16+mr
    const int mblk = blockIdx.x * 4 + w;
    #pragma unroll
    for (int n = 0; n < 4; ++n) {
        const int rb = n * 2 + (mr >> 3), j = mr & 7;
        #pragma unroll
        for (int q = 0; q < 4; ++q)
            inter2[i2_idx(mblk, rb, kg * 4 + q, j)] = (__bf16)acc[n][q];
    }
}

// ---------------------------------------------------------------------------
// k_by: out = base + s * (inter @ B).  (R8/R11/R13 verbatim, ~6.5 TB/s)
// ---------------------------------------------------------------------------
__global__ __launch_bounds__(256) void k_by(
    const __bf16* __restrict__ inter2, const float* __restrict__ base,
    const int* __restrict__ idx, const __bf16* __restrict__ Bp,
    const float* __restrict__ scal, float* __restrict__ out)
{
    const int o0 = blockIdx.x * 64;
    const int m0 = blockIdx.y * 64;
    const int a  = idx[m0 / TSEQ];
    const float s = scal[a];
    const __bf16* __restrict__ Ba = Bp + (size_t)a * RR * DOUT;
    const int lane = threadIdx.x & 63;
    const int w    = threadIdx.x >> 6;
    const int mr   = lane & 15, kg = lane >> 4;
    const int oc   = o0 + w * 16 + mr;

    f32x4 z = {0.f, 0.f, 0.f, 0.f};
    f32x4 acc[4] = {z, z, z, z};

    #pragma unroll
    for (int ksub = 0; ksub < 2; ++ksub) {
        const int rb = ksub * 4 + kg;
        bf16x8 bfA = *(const bf16x8*)&Ba[((size_t)rb * DOUT + oc) * 8];
        #pragma unroll
        for (int mt = 0; mt < 4; ++mt) {
            bf16x8 afB = *(const bf16x8*)&inter2[i2_idx(m0 / 16 + mt, rb, mr, 0)];
            acc[mt] = __builtin_amdgcn_mfma_f32_16x16x32_bf16(bfA, afB, acc[mt], 0, 0, 0);
        }
    }

    #pragma unroll
    for (int mt = 0; mt < 4; ++mt) {
        size_t off = (size_t)(m0 + mt * 16 + mr) * DOUT + o0 + w * 16 + kg * 4;
        float4 bv = *(const float4*)&base[off];
        float4 o;
        o.x = bv.x + s * acc[mt][0];
        o.y = bv.y + s * acc[mt][1];
        o.z = bv.z + s * acc[mt][2];
        o.w = bv.w + s * acc[mt][3];
        *(float4*)&out[off] = o;
    }
}

// ---------------------------------------------------------------------------
// Fallback kernels (R6 verbatim, 2 MB ws) if ws_size < 10 MB.
// ---------------------------------------------------------------------------
__global__ __launch_bounds__(256) void k_xa_fb(
    const float* __restrict__ x, const int* __restrict__ idx,
    const float* __restrict__ A, __bf16* __restrict__ inter)
{
    const int m0   = blockIdx.x * 32;
    const int a    = idx[m0 / TSEQ];
    const float* __restrict__ Aa = A + (size_t)a * DIN * RR;
    const int lane = threadIdx.x & 63;
    const int rw   = threadIdx.x >> 6;
    const int mr   = lane & 15, kg = lane >> 4;
    const int rcol = rw * 16 + mr;
    const float* __restrict__ xrow0 = x + (size_t)(m0 + mr) * DIN;
    const float* __restrict__ xrow1 = x + (size_t)(m0 + 16 + mr) * DIN;

    f32x4 acc0 = {0.f, 0.f, 0.f, 0.f};
    f32x4 acc1 = {0.f, 0.f, 0.f, 0.f};

    for (int k0 = 0; k0 < DIN; k0 += 64) {
        #pragma unroll
        for (int ksub = 0; ksub < 2; ++ksub) {
            const int koff = k0 + ksub * 32 + kg * 8;
            float4 u0 = *(const float4*)&xrow0[koff];
            float4 u1 = *(const float4*)&xrow0[koff + 4];
            float4 v0 = *(const float4*)&xrow1[koff];
            float4 v1 = *(const float4*)&xrow1[koff + 4];
            bf16x8 af0 = cvt8(u0, u1);
            bf16x8 af1 = cvt8(v0, v1);
            const float* ap = &Aa[(size_t)koff * RR + rcol];
            bf16x8 bf;
            bf[0] = (__bf16)ap[0 * RR]; bf[1] = (__bf16)ap[1 * RR];
            bf[2] = (__bf16)ap[2 * RR]; bf[3] = (__bf16)ap[3 * RR];
            bf[4] = (__bf16)ap[4 * RR]; bf[5] = (__bf16)ap[5 * RR];
            bf[6] = (__bf16)ap[6 * RR]; bf[7] = (__bf16)ap[7 * RR];
            acc0 = __builtin_amdgcn_mfma_f32_16x16x32_bf16(af0, bf, acc0, 0, 0, 0);
            acc1 = __builtin_amdgcn_mfma_f32_16x16x32_bf16(af1, bf, acc1, 0, 0, 0);
        }
    }
    #pragma unroll
    for (int q = 0; q < 4; ++q) {
        inter[(size_t)(m0 + kg * 4 + q) * RR + rcol]      = (__bf16)acc0[q];
        inter[(size_t)(m0 + 16 + kg * 4 + q) * RR + rcol] = (__bf16)acc1[q];
    }
}

__global__ __launch_bounds__(256) void k_by_fb(
    const __bf16* __restrict__ inter, const float* __restrict__ base,
    const int* __restrict__ idx, const float* __restrict__ Bw,
    const float* __restrict__ scal, float* __restrict__ out)
{
    const int o0 = blockIdx.x * 64;
    const int m0 = blockIdx.y * 64;
    const int a  = idx[m0 / TSEQ];
    const float s = scal[a];
    const float* __restrict__ Ba = Bw + (size_t)a * RR * DOUT;
    const int lane = threadIdx.x & 63;
    const int w    = threadIdx.x >> 6;
    const int mr   = lane & 15, kg = lane >> 4;
    const int oc   = o0 + w * 16 + mr;

    f32x4 z = {0.f, 0.f, 0.f, 0.f};
    f32x4 acc[4] = {z, z, z, z};

    #pragma unroll
    for (int ksub = 0; ksub < 2; ++ksub) {
        const int kb = ksub * 32 + kg * 8;
        const float* bp = &Ba[(size_t)kb * DOUT + oc];
        bf16x8 bf;
        bf[0] = (__bf16)bp[0 * DOUT]; bf[1] = (__bf16)bp[1 * DOUT];
        bf[2] = (__bf16)bp[2 * DOUT]; bf[3] = (__bf16)bp[3 * DOUT];
        bf[4] = (__bf16)bp[4 * DOUT]; bf[5] = (__bf16)bp[5 * DOUT];
        bf[6] = (__bf16)bp[6 * DOUT]; bf[7] = (__bf16)bp[7 * DOUT];
        #pragma unroll
        for (int mt = 0; mt < 4; ++mt) {
            bf16x8 af = *(const bf16x8*)&inter[(size_t)(m0 + mt * 16 + mr) * RR + kb];
            acc[mt] = __builtin_amdgcn_mfma_f32_16x16x32_bf16(af, bf, acc[mt], 0, 0, 0);
        }
    }
    #pragma unroll
    for (int mt = 0; mt < 4; ++mt) {
        #pragma unroll
        for (int q = 0; q < 4; ++q) {
            size_t off = (size_t)(m0 + mt * 16 + kg * 4 + q) * DOUT + oc;
            out[off] = base[off] + s * acc[mt][q];
        }
    }
}

// ---------------------------------------------------------------------------
extern "C" void kernel_launch(void* const* d_in, const int* in_sizes, int n_in,
                              void* d_out, int out_size, void* d_ws, size_t ws_size,
                              hipStream_t stream)
{
    const float* x    = (const float*)d_in[0];
    const float* base = (const float*)d_in[1];
    const int*   idx  = (const int*)  d_in[2];
    const float* A    = (const float*)d_in[3];
    const float* Bw   = (const float*)d_in[4];
    const float* scal = (const float*)d_in[5];
    float* out = (float*)d_out;

    const size_t INTER_B = (size_t)BT * RR * 2;              // 2 MB
    const size_t AT_B    = (size_t)NADP * RR * DIN * 2;      // 4 MB
    const size_t BT_B    = (size_t)NADP * DOUT * RR * 2;     // 4 MB

    if (ws_size >= INTER_B + AT_B + BT_B) {                  // 10 MB path
        __bf16* inter2 = (__bf16*)d_ws;
        __bf16* At2    = (__bf16*)((char*)d_ws + INTER_B);
        __bf16* Bp     = (__bf16*)((char*)d_ws + INTER_B + AT_B);
        k_prep_a<<<dim3(1024), 256, 0, stream>>>(A, At2);
        k_prep_b<<<dim3(1024), 256, 0, stream>>>(Bw, Bp);
        k_xa<<<dim3(BT / 64),            256, 0, stream>>>(x, idx, At2, inter2);
        k_by<<<dim3(DOUT / 64, BT / 64), 256, 0, stream>>>(inter2, base, idx, Bp, scal, out);
    } else {                                                 // 2 MB fallback
        __bf16* inter = (__bf16*)d_ws;
        k_xa_fb<<<dim3(BT / 32),            256, 0, stream>>>(x, idx, A, inter);
        k_by_fb<<<dim3(DOUT / 64, BT / 64), 256, 0, stream>>>(inter, base, idx, Bw, scal, out);
    }
}

// Round 15
// 206.774 us; speedup vs baseline: 1.0489x; 1.0489x over previous
//
#include <hip/hip_runtime.h>
#include <hip/hip_bf16.h>
#include <cstdint>
#include <cstddef>

#define BT    16384   // B*T
#define DIN   4096
#define DOUT  4096
#define RR    64
#define TSEQ  2048
#define NADP  8

typedef float  f32x4  __attribute__((ext_vector_type(4)));
typedef __bf16 bf16x8 __attribute__((ext_vector_type(8)));

static __device__ __forceinline__ unsigned short bf16_bits(float f) {
    return __builtin_bit_cast(unsigned short, (__bf16)f);
}

// inter2 swizzled layout: [mblk(1024)][rb(8)][mrow(16)][j(8)]
static __device__ __forceinline__ size_t i2_idx(int mblk, int rb, int mrow, int j) {
    return ((((size_t)mblk * 8 + rb) * 16 + mrow) * 8 + j);
}

static __device__ __forceinline__ bf16x8 cvt8(float4 a, float4 b) {
    bf16x8 v;
    v[0] = (__bf16)a.x; v[1] = (__bf16)a.y; v[2] = (__bf16)a.z; v[3] = (__bf16)a.w;
    v[4] = (__bf16)b.x; v[5] = (__bf16)b.y; v[6] = (__bf16)b.z; v[7] = (__bf16)b.w;
    return v;
}

static __device__ __forceinline__ bf16x8 cvt8v(f32x4 a, f32x4 b) {
    bf16x8 v;
    v[0] = (__bf16)a[0]; v[1] = (__bf16)a[1]; v[2] = (__bf16)a[2]; v[3] = (__bf16)a[3];
    v[4] = (__bf16)b[0]; v[5] = (__bf16)b[1]; v[6] = (__bf16)b[2]; v[7] = (__bf16)b[3];
    return v;
}

// global -> LDS direct copy, 16 bytes per lane. LDS dest is wave-uniform
// base + lane*16 (HW); global src is per-lane. Addrspace casts via integer
// round-trip (flat->local lowering = low 32 bits).
typedef const __attribute__((address_space(1))) void* gas1_t;
typedef __attribute__((address_space(3))) void*       gas3_t;
static __device__ __forceinline__ void gll16(const void* g, void* l) {
    __builtin_amdgcn_global_load_lds((gas1_t)(uintptr_t)g,
                                     (gas3_t)(uint32_t)(uintptr_t)l,
                                     16, 0, 0);
}

// ---------------------------------------------------------------------------
// k_prep_a: At2[a][kq][r][j] = bf16(A[a][kq*8+j][r]).  (R8+ verbatim)
// ---------------------------------------------------------------------------
__global__ __launch_bounds__(256) void k_prep_a(
    const float* __restrict__ A, __bf16* __restrict__ At2)
{
    const int gtid = blockIdx.x * 256 + threadIdx.x;
    const int r  = gtid & 63;
    const int kb = (gtid >> 6) & (DIN / 8 - 1);
    const int a  = gtid >> 15;
    const float* __restrict__ src = A + (size_t)a * DIN * RR + (size_t)kb * 8 * RR + r;
    unsigned int u[4];
    #pragma unroll
    for (int p = 0; p < 4; ++p) {
        unsigned int lo = bf16_bits(src[(2 * p + 0) * RR]);
        unsigned int hi = bf16_bits(src[(2 * p + 1) * RR]);
        u[p] = lo | (hi << 16);
    }
    *(uint4*)&At2[(size_t)gtid * 8] = make_uint4(u[0], u[1], u[2], u[3]);
}

// ---------------------------------------------------------------------------
// k_prep_b: Bp[a][rb][o][j] = bf16(B[a][rb*8+j][o]).  (R8+ verbatim)
// ---------------------------------------------------------------------------
__global__ __launch_bounds__(256) void k_prep_b(
    const float* __restrict__ Bw, __bf16* __restrict__ Bp)
{
    const int gtid = blockIdx.x * 256 + threadIdx.x;
    const int o  = gtid & (DOUT - 1);
    const int rb = (gtid >> 12) & 7;
    const int a  = gtid >> 15;
    const float* __restrict__ src = Bw + (size_t)a * RR * DOUT + (size_t)rb * 8 * DOUT + o;
    unsigned int u[4];
    #pragma unroll
    for (int p = 0; p < 4; ++p) {
        unsigned int lo = bf16_bits(src[(2 * p + 0) * DOUT]);
        unsigned int hi = bf16_bits(src[(2 * p + 1) * DOUT]);
        u[p] = lo | (hi << 16);
    }
    *(uint4*)&Bp[(size_t)gtid * 8] = make_uint4(u[0], u[1], u[2], u[3]);
}

// ---------------------------------------------------------------------------
// k_xa: inter2 <- bf16( x @ A[a] ).  m97-style global_load_lds staging.
// grid 512 blocks (32 m-rows) x 4 waves, 2 blocks/CU. Per K-tile (BK=64):
// 8 KB fp32 x-tile staged direct-to-LDS (8 x gll16, no VGPR round-trip),
// double-buffered; 2-barrier loop: STAGE(t+1) || COMPUTE(t) -> barrier.
// Source slots XOR-pre-swizzled (G21): LDS[row][p] holds global slot
// p ^ (row&15) -> ds_read of logical slot l at phys l^(row&15): 2-way max.
// Wave w: r-tile [w*16,+16), rows 0-31 (2 chains).  Output = R13 convention.
// ---------------------------------------------------------------------------
__global__ __launch_bounds__(256, 2) void k_xa(
    const float* __restrict__ x, const int* __restrict__ idx,
    const __bf16* __restrict__ At2, __bf16* __restrict__ inter2)
{
    __shared__ float xs[2][32][64];    // 16 KB, double-buffered fp32 x-tile

    const int m0   = blockIdx.x * 32;
    const int a    = idx[m0 / TSEQ];
    const int w    = threadIdx.x >> 6, lane = threadIdx.x & 63;
    const int mr   = lane & 15, kg = lane >> 4;
    const int rcol = w * 16 + mr;

    const __bf16* __restrict__ Aw = At2 + (size_t)a * RR * DIN;

    // staging: wave w instr i stages rows w*8+i*4 .. +3 (lane>>4 = row-in-4);
    // per-lane source slot is XOR-swizzled by row; LDS dest linear.
    const float* gsrc0;
    const float* gsrc1;
    {
        const int R0 = w * 8 + 0 * 4 + kg;
        const int R1 = w * 8 + 1 * 4 + kg;
        const int s0 = (lane & 15) ^ (R0 & 15);
        const int s1 = (lane & 15) ^ (R1 & 15);
        gsrc0 = x + (size_t)(m0 + R0) * DIN + s0 * 4;
        gsrc1 = x + (size_t)(m0 + R1) * DIN + s1 * 4;
    }

    f32x4 z = {0.f, 0.f, 0.f, 0.f};
    f32x4 acc0 = z, acc1 = z;

#define STAGE(B, T)                                                      \
    {                                                                    \
        gll16(gsrc0 + (T) * 64, &xs[B][w * 8 + 0][0]);                   \
        gll16(gsrc1 + (T) * 64, &xs[B][w * 8 + 4][0]);                   \
    }

#define COMPUTE(B, T)                                                              \
    {                                                                              \
        _Pragma("unroll")                                                          \
        for (int ksub = 0; ksub < 2; ++ksub) {                                     \
            const int kq = ksub * 4 + kg;                                          \
            bf16x8 bfw = *(const bf16x8*)&Aw[(((size_t)(T) * 8 + kq) * 64 + rcol) * 8]; \
            f32x4 lo0 = *(const f32x4*)&xs[B][mr]     [((2 * kq)     ^ mr) * 4];   \
            f32x4 hi0 = *(const f32x4*)&xs[B][mr]     [((2 * kq + 1) ^ mr) * 4];   \
            f32x4 lo1 = *(const f32x4*)&xs[B][16 + mr][((2 * kq)     ^ mr) * 4];   \
            f32x4 hi1 = *(const f32x4*)&xs[B][16 + mr][((2 * kq + 1) ^ mr) * 4];   \
            acc0 = __builtin_amdgcn_mfma_f32_16x16x32_bf16(cvt8v(lo0, hi0), bfw, acc0, 0, 0, 0); \
            acc1 = __builtin_amdgcn_mfma_f32_16x16x32_bf16(cvt8v(lo1, hi1), bfw, acc1, 0, 0, 0); \
        }                                                                          \
    }

    STAGE(0, 0)
    __syncthreads();

    for (int t = 0; t < 63; ++t) {
        STAGE((t + 1) & 1, t + 1)     // issue next tile direct-to-LDS
        COMPUTE(t & 1, t)             // overlaps with staging flight time
        __syncthreads();              // drain: next buffer ready
    }
    COMPUTE(1, 63)

#undef STAGE
#undef COMPUTE

    // D layout (R13-proven): m = m0 + mf*16 + kg*4+q, r = rcol
    const int rb = w * 2 + (mr >> 3), j = mr & 7;
    #pragma unroll
    for (int q = 0; q < 4; ++q) {
        inter2[i2_idx(blockIdx.x * 2 + 0, rb, kg * 4 + q, j)] = (__bf16)acc0[q];
        inter2[i2_idx(blockIdx.x * 2 + 1, rb, kg * 4 + q, j)] = (__bf16)acc1[q];
    }
}

// ---------------------------------------------------------------------------
// k_by: out = base + s * (inter @ B).  (R8/R11/R13 verbatim, ~6.5 TB/s)
// ---------------------------------------------------------------------------
__global__ __launch_bounds__(256) void k_by(
    const __bf16* __restrict__ inter2, const float* __restrict__ base,
    const int* __restrict__ idx, const __bf16* __restrict__ Bp,
    const float* __restrict__ scal, float* __restrict__ out)
{
    const int o0 = blockIdx.x * 64;
    const int m0 = blockIdx.y * 64;
    const int a  = idx[m0 / TSEQ];
    const float s = scal[a];
    const __bf16* __restrict__ Ba = Bp + (size_t)a * RR * DOUT;
    const int lane = threadIdx.x & 63;
    const int w    = threadIdx.x >> 6;
    const int mr   = lane & 15, kg = lane >> 4;
    const int oc   = o0 + w * 16 + mr;

    f32x4 z = {0.f, 0.f, 0.f, 0.f};
    f32x4 acc[4] = {z, z, z, z};

    #pragma unroll
    for (int ksub = 0; ksub < 2; ++ksub) {
        const int rb = ksub * 4 + kg;
        bf16x8 bfA = *(const bf16x8*)&Ba[((size_t)rb * DOUT + oc) * 8];
        #pragma unroll
        for (int mt = 0; mt < 4; ++mt) {
            bf16x8 afB = *(const bf16x8*)&inter2[i2_idx(m0 / 16 + mt, rb, mr, 0)];
            acc[mt] = __builtin_amdgcn_mfma_f32_16x16x32_bf16(bfA, afB, acc[mt], 0, 0, 0);
        }
    }

    #pragma unroll
    for (int mt = 0; mt < 4; ++mt) {
        size_t off = (size_t)(m0 + mt * 16 + mr) * DOUT + o0 + w * 16 + kg * 4;
        float4 bv = *(const float4*)&base[off];
        float4 o;
        o.x = bv.x + s * acc[mt][0];
        o.y = bv.y + s * acc[mt][1];
        o.z = bv.z + s * acc[mt][2];
        o.w = bv.w + s * acc[mt][3];
        *(float4*)&out[off] = o;
    }
}

// ---------------------------------------------------------------------------
// Fallback kernels (R6 verbatim, 2 MB ws) if ws_size < 10 MB.
// ---------------------------------------------------------------------------
__global__ __launch_bounds__(256) void k_xa_fb(
    const float* __restrict__ x, const int* __restrict__ idx,
    const float* __restrict__ A, __bf16* __restrict__ inter)
{
    const int m0   = blockIdx.x * 32;
    const int a    = idx[m0 / TSEQ];
    const float* __restrict__ Aa = A + (size_t)a * DIN * RR;
    const int lane = threadIdx.x & 63;
    const int rw   = threadIdx.x >> 6;
    const int mr   = lane & 15, kg = lane >> 4;
    const int rcol = rw * 16 + mr;
    const float* __restrict__ xrow0 = x + (size_t)(m0 + mr) * DIN;
    const float* __restrict__ xrow1 = x + (size_t)(m0 + 16 + mr) * DIN;

    f32x4 acc0 = {0.f, 0.f, 0.f, 0.f};
    f32x4 acc1 = {0.f, 0.f, 0.f, 0.f};

    for (int k0 = 0; k0 < DIN; k0 += 64) {
        #pragma unroll
        for (int ksub = 0; ksub < 2; ++ksub) {
            const int koff = k0 + ksub * 32 + kg * 8;
            float4 u0 = *(const float4*)&xrow0[koff];
            float4 u1 = *(const float4*)&xrow0[koff + 4];
            float4 v0 = *(const float4*)&xrow1[koff];
            float4 v1 = *(const float4*)&xrow1[koff + 4];
            bf16x8 af0 = cvt8(u0, u1);
            bf16x8 af1 = cvt8(v0, v1);
            const float* ap = &Aa[(size_t)koff * RR + rcol];
            bf16x8 bf;
            bf[0] = (__bf16)ap[0 * RR]; bf[1] = (__bf16)ap[1 * RR];
            bf[2] = (__bf16)ap[2 * RR]; bf[3] = (__bf16)ap[3 * RR];
            bf[4] = (__bf16)ap[4 * RR]; bf[5] = (__bf16)ap[5 * RR];
            bf[6] = (__bf16)ap[6 * RR]; bf[7] = (__bf16)ap[7 * RR];
            acc0 = __builtin_amdgcn_mfma_f32_16x16x32_bf16(af0, bf, acc0, 0, 0, 0);
            acc1 = __builtin_amdgcn_mfma_f32_16x16x32_bf16(af1, bf, acc1, 0, 0, 0);
        }
    }
    #pragma unroll
    for (int q = 0; q < 4; ++q) {
        inter[(size_t)(m0 + kg * 4 + q) * RR + rcol]      = (__bf16)acc0[q];
        inter[(size_t)(m0 + 16 + kg * 4 + q) * RR + rcol] = (__bf16)acc1[q];
    }
}

__global__ __launch_bounds__(256) void k_by_fb(
    const __bf16* __restrict__ inter, const float* __restrict__ base,
    const int* __restrict__ idx, const float* __restrict__ Bw,
    const float* __restrict__ scal, float* __restrict__ out)
{
    const int o0 = blockIdx.x * 64;
    const int m0 = blockIdx.y * 64;
    const int a  = idx[m0 / TSEQ];
    const float s = scal[a];
    const float* __restrict__ Ba = Bw + (size_t)a * RR * DOUT;
    const int lane = threadIdx.x & 63;
    const int w    = threadIdx.x >> 6;
    const int mr   = lane & 15, kg = lane >> 4;
    const int oc   = o0 + w * 16 + mr;

    f32x4 z = {0.f, 0.f, 0.f, 0.f};
    f32x4 acc[4] = {z, z, z, z};

    #pragma unroll
    for (int ksub = 0; ksub < 2; ++ksub) {
        const int kb = ksub * 32 + kg * 8;
        const float* bp = &Ba[(size_t)kb * DOUT + oc];
        bf16x8 bf;
        bf[0] = (__bf16)bp[0 * DOUT]; bf[1] = (__bf16)bp[1 * DOUT];
        bf[2] = (__bf16)bp[2 * DOUT]; bf[3] = (__bf16)bp[3 * DOUT];
        bf[4] = (__bf16)bp[4 * DOUT]; bf[5] = (__bf16)bp[5 * DOUT];
        bf[6] = (__bf16)bp[6 * DOUT]; bf[7] = (__bf16)bp[7 * DOUT];
        #pragma unroll
        for (int mt = 0; mt < 4; ++mt) {
            bf16x8 af = *(const bf16x8*)&inter[(size_t)(m0 + mt * 16 + mr) * RR + kb];
            acc[mt] = __builtin_amdgcn_mfma_f32_16x16x32_bf16(af, bf, acc[mt], 0, 0, 0);
        }
    }
    #pragma unroll
    for (int mt = 0; mt < 4; ++mt) {
        #pragma unroll
        for (int q = 0; q < 4; ++q) {
            size_t off = (size_t)(m0 + mt * 16 + kg * 4 + q) * DOUT + oc;
            out[off] = base[off] + s * acc[mt][q];
        }
    }
}

// ---------------------------------------------------------------------------
extern "C" void kernel_launch(void* const* d_in, const int* in_sizes, int n_in,
                              void* d_out, int out_size, void* d_ws, size_t ws_size,
                              hipStream_t stream)
{
    const float* x    = (const float*)d_in[0];
    const float* base = (const float*)d_in[1];
    const int*   idx  = (const int*)  d_in[2];
    const float* A    = (const float*)d_in[3];
    const float* Bw   = (const float*)d_in[4];
    const float* scal = (const float*)d_in[5];
    float* out = (float*)d_out;

    const size_t INTER_B = (size_t)BT * RR * 2;              // 2 MB
    const size_t AT_B    = (size_t)NADP * RR * DIN * 2;      // 4 MB
    const size_t BT_B    = (size_t)NADP * DOUT * RR * 2;     // 4 MB

    if (ws_size >= INTER_B + AT_B + BT_B) {                  // 10 MB path
        __bf16* inter2 = (__bf16*)d_ws;
        __bf16* At2    = (__bf16*)((char*)d_ws + INTER_B);
        __bf16* Bp     = (__bf16*)((char*)d_ws + INTER_B + AT_B);
        k_prep_a<<<dim3(1024), 256, 0, stream>>>(A, At2);
        k_prep_b<<<dim3(1024), 256, 0, stream>>>(Bw, Bp);
        k_xa<<<dim3(BT / 32),            256, 0, stream>>>(x, idx, At2, inter2);
        k_by<<<dim3(DOUT / 64, BT / 64), 256, 0, stream>>>(inter2, base, idx, Bp, scal, out);
    } else {                                                 // 2 MB fallback
        __bf16* inter = (__bf16*)d_ws;
        k_xa_fb<<<dim3(BT / 32),            256, 0, stream>>>(x, idx, A, inter);
        k_by_fb<<<dim3(DOUT / 64, BT / 64), 256, 0, stream>>>(inter, base, idx, Bw, scal, out);
    }
}